// Round 10
// baseline (327.856 us; speedup 1.0000x reference)
//
#include <hip/hip_runtime.h>
#include <hip/hip_fp16.h>

#define ND 64
#define BG 128        // dst ids per bucket
#define MAXB 1024     // max buckets (LDS sizing); nb = ceil(2N/BG) = 782
#define PCH 16384     // edges per partition chunk: 196 part-blocks
#define CAP 4608      // per-bucket slab capacity; lambda=4096, sigma~64 -> 8-sigma margin

__device__ __forceinline__ float lrelu(float x) { return x > 0.f ? x : 0.2f * x; }

__device__ __forceinline__ float wave_sum(float v) {
#pragma unroll
    for (int m = 32; m > 0; m >>= 1) v += __shfl_xor(v, m, 64);
    return v;
}

// 8 fp16 x fp32 fused into 8 fp32 accumulators (v_fma_mix_f32 form)
__device__ __forceinline__ void fma8(float* acc, float w, int4 raw) {
    union { int4 i; __half h[8]; } u;
    u.i = raw;
#pragma unroll
    for (int i = 0; i < 8; i++) acc[i] = fmaf(w, __half2float(u.h[i]), acc[i]);
}

// ---------------- bucketed CSR build (fixed-capacity slabs) ----------------
// bcursor is zeroed via hipMemsetAsync; cursors are RELATIVE (run offset
// within bucket b's slab at b*CAP).

__device__ void partition_body(int* hist, int* lcur,
                               const int* __restrict__ eI, const int* __restrict__ eP,
                               int* __restrict__ bcursor, int* __restrict__ part,
                               int N, int E, int nb) {
    int t = threadIdx.x;
    int total = 2 * E;
    int chunkBase = blockIdx.x * PCH;
    int cnt = min(PCH, total - chunkBase);
    if (t < nb) hist[t] = 0;
    __syncthreads();

    if (cnt == PCH) {
        int pk[16];
        unsigned bkp[8];
#pragma unroll
        for (int it = 0; it < 4; it++) {
            int i = t * 4 + it * 4096;
            int e = chunkBase + i;
            int sv[4], dv[4];
            if (e + 3 < E) {
                int4 a = *(const int4*)(eI + e);
                int4 b = *(const int4*)(eI + E + e);
                sv[0] = a.x; sv[1] = a.y; sv[2] = a.z; sv[3] = a.w;
                dv[0] = b.x; dv[1] = b.y; dv[2] = b.z; dv[3] = b.w;
            } else if (e >= E) {
                int4 a = *(const int4*)(eP + (e - E));
                int4 b = *(const int4*)(eP + E + (e - E));
                sv[0] = a.x; sv[1] = a.y; sv[2] = a.z; sv[3] = a.w;
                dv[0] = b.x + N; dv[1] = b.y + N; dv[2] = b.z + N; dv[3] = b.w + N;
            } else {
#pragma unroll
                for (int k = 0; k < 4; k++) {
                    int ee = e + k;
                    if (ee < E) { sv[k] = eI[ee]; dv[k] = eI[E + ee]; }
                    else        { sv[k] = eP[ee - E]; dv[k] = N + eP[E + ee - E]; }
                }
            }
#pragma unroll
            for (int k = 0; k < 4; k++) {
                int j = it * 4 + k;
                int bk = dv[k] >> 7;
                pk[j] = (sv[k] << 8) | (dv[k] & 255);
                atomicAdd(&hist[bk], 1);
                if ((j & 1) == 0) bkp[j >> 1] = (unsigned)bk;
                else bkp[j >> 1] |= (unsigned)bk << 16;
            }
        }
        __syncthreads();
        if (t < nb) lcur[t] = t * CAP + (hist[t] ? atomicAdd(&bcursor[t], hist[t]) : 0);
        __syncthreads();
#pragma unroll
        for (int j = 0; j < 16; j++) {
            int bk = (bkp[j >> 1] >> ((j & 1) * 16)) & 0xffff;
            int pos = atomicAdd(&lcur[bk], 1);
            part[pos] = pk[j];
        }
        return;
    }

    // slow path (tail chunk only)
    int cnt4 = cnt & ~3;
    for (int i = t * 4; i < cnt4; i += 4096) {
        int e = chunkBase + i;
        int4 d; int base;
        if (e + 3 < E)   { d = *(const int4*)(eI + E + e); base = 0; }
        else if (e >= E) { d = *(const int4*)(eP + E + (e - E)); base = N; }
        else {
            int tmp[4];
#pragma unroll
            for (int k = 0; k < 4; k++) {
                int ee = e + k;
                tmp[k] = (ee < E) ? eI[E + ee] : N + eP[E + ee - E];
            }
            d = make_int4(tmp[0], tmp[1], tmp[2], tmp[3]); base = 0;
        }
        atomicAdd(&hist[(base + d.x) >> 7], 1);
        atomicAdd(&hist[(base + d.y) >> 7], 1);
        atomicAdd(&hist[(base + d.z) >> 7], 1);
        atomicAdd(&hist[(base + d.w) >> 7], 1);
    }
    for (int i = cnt4 + t; i < cnt; i += 1024) {
        int e = chunkBase + i;
        int idx = (e < E) ? eI[E + e] : N + eP[E + (e - E)];
        atomicAdd(&hist[idx >> 7], 1);
    }
    __syncthreads();
    if (t < nb) lcur[t] = t * CAP + (hist[t] ? atomicAdd(&bcursor[t], hist[t]) : 0);
    __syncthreads();
    for (int i = t; i < cnt; i += 1024) {
        int e = chunkBase + i;
        int s, idx;
        if (e < E) { s = eI[e]; idx = eI[E + e]; }
        else       { s = eP[e - E]; idx = N + eP[E + (e - E)]; }
        int pos = atomicAdd(&lcur[idx >> 7], 1);
        part[pos] = (s << 8) | (idx & 255);
    }
}

// ---- gemm body: h(fp16) = x @ W + score dots; 16 waves/block, 4 nodes/wave ----
__device__ void gemm_body(float* xsAll, int gb,
                          const float* __restrict__ xA, const float* __restrict__ xB,
                          const float* __restrict__ WA, const float* __restrict__ WB,
                          const float* __restrict__ asA, const float* __restrict__ adA,
                          const float* __restrict__ asB, const float* __restrict__ adB,
                          __half* __restrict__ h16, float* __restrict__ ssrc,
                          float* __restrict__ sdst, int N) {
    int half = gb & 1;
    int blk = gb >> 1;
    int wave = threadIdx.x >> 6;
    int lane = threadIdx.x & 63;
    const float* x  = half ? xB : xA;
    const float* W  = half ? WB : WA;
    const float* av_ = half ? asB : asA;
    const float* dv_ = half ? adB : adA;
    int nodeBase = (blk * 16 + wave) * 4;      // within half
    float* xs = xsAll + wave * (4 * ND);

    if (nodeBase + 3 < N) {
        *(float4*)&xs[lane * 4] = *(const float4*)&x[(size_t)nodeBase * ND + lane * 4];
    } else if (nodeBase < N) {
#pragma unroll
        for (int i = 0; i < 4; i++) {
            int gi = nodeBase * ND + lane * 4 + i;
            xs[lane * 4 + i] = (gi < N * ND) ? x[gi] : 0.f;
        }
    }
    __syncthreads();
    if (nodeBase >= N) return;

    float4 acc = {0.f, 0.f, 0.f, 0.f};
#pragma unroll
    for (int k = 0; k < ND; k++) {
        float wv = W[k * ND + lane];
        acc.x = fmaf(xs[0 * ND + k], wv, acc.x);
        acc.y = fmaf(xs[1 * ND + k], wv, acc.y);
        acc.z = fmaf(xs[2 * ND + k], wv, acc.z);
        acc.w = fmaf(xs[3 * ND + k], wv, acc.w);
    }
    float av = av_[lane], dv = dv_[lane];
    float s1x = wave_sum(acc.x * av), s2x = wave_sum(acc.x * dv);
    float s1y = wave_sum(acc.y * av), s2y = wave_sum(acc.y * dv);
    float s1z = wave_sum(acc.z * av), s2z = wave_sum(acc.z * dv);
    float s1w = wave_sum(acc.w * av), s2w = wave_sum(acc.w * dv);

    int g0 = half * N + nodeBase;
    h16[(size_t)(g0 + 0) * ND + lane] = __float2half(acc.x);
    if (nodeBase + 1 < N) h16[(size_t)(g0 + 1) * ND + lane] = __float2half(acc.y);
    if (nodeBase + 2 < N) h16[(size_t)(g0 + 2) * ND + lane] = __float2half(acc.z);
    if (nodeBase + 3 < N) h16[(size_t)(g0 + 3) * ND + lane] = __float2half(acc.w);
    if (lane == 0) {
        ssrc[g0] = s1x; sdst[g0] = s2x;
        if (nodeBase + 1 < N) { ssrc[g0 + 1] = s1y; sdst[g0 + 1] = s2y; }
        if (nodeBase + 2 < N) { ssrc[g0 + 2] = s1z; sdst[g0 + 2] = s2z; }
        if (nodeBase + 3 < N) { ssrc[g0 + 3] = s1w; sdst[g0 + 3] = s2w; }
    }
}

// ---- fused: partition (blocks < partBlocks) | layer-1 gemm (the rest) ----
__global__ void __launch_bounds__(1024) part_gemm(
        const int* __restrict__ eI, const int* __restrict__ eP,
        int* __restrict__ bcursor, int* __restrict__ part,
        const float* __restrict__ xA, const float* __restrict__ xB,
        const float* __restrict__ WA, const float* __restrict__ WB,
        const float* __restrict__ asA, const float* __restrict__ adA,
        const float* __restrict__ asB, const float* __restrict__ adB,
        __half* __restrict__ h16, float* __restrict__ ssrc, float* __restrict__ sdst,
        int N, int E, int nb, int partBlocks) {
    __shared__ int smem[16 * 4 * ND];   // 16 KB
    if (blockIdx.x < partBlocks) {
        partition_body(smem, smem + MAXB, eI, eP, bcursor, part, N, E, nb);
    } else {
        gemm_body((float*)smem, blockIdx.x - partBlocks,
                  xA, xB, WA, WB, asA, adA, asB, adB, h16, ssrc, sdst, N);
    }
}

// one block (1024 thr) per bucket: hist + wave-shfl scan -> row/deg, LDS
// scatter + per-key insertion sort by src (deterministic csr), int4 copy-out.
__global__ void bucket_build(const int* __restrict__ part, const int* __restrict__ bcursor,
                             int* __restrict__ row, int* __restrict__ deg,
                             int* __restrict__ csr, int n2, int N) {
    __shared__ int lhist[BG * 8];
    __shared__ int lrow[BG * 8];
    __shared__ int slab[CAP];
    __shared__ int wsum[16];
    int b = blockIdx.x, t = threadIdx.x;
    int lane = t & 63, wave = t >> 6;
    int start = b * CAP;
    int cnt = min(bcursor[b], CAP);
    int cnt4 = cnt & ~3;
    int t1 = (N * 1) >> 3, t2 = (N * 2) >> 3, t3 = (N * 3) >> 3, t4 = (N * 4) >> 3;
    int t5 = (N * 5) >> 3, t6 = (N * 6) >> 3, t7 = (N * 7) >> 3;
    auto key = [&](int p) {
        int s = p >> 8;
        int o = (s >= t1) + (s >= t2) + (s >= t3) + (s >= t4)
              + (s >= t5) + (s >= t6) + (s >= t7);
        return ((p & 127) << 3) | o;
    };
    lhist[t] = 0;
    __syncthreads();
    for (int j = t * 4; j < cnt4; j += 4096) {
        int4 p = *(const int4*)(part + start + j);
        atomicAdd(&lhist[key(p.x)], 1);
        atomicAdd(&lhist[key(p.y)], 1);
        atomicAdd(&lhist[key(p.z)], 1);
        atomicAdd(&lhist[key(p.w)], 1);
    }
    for (int j = cnt4 + t; j < cnt; j += 1024) atomicAdd(&lhist[key(part[start + j])], 1);
    __syncthreads();
    int v = lhist[t];
    // wave-level inclusive scan (64 lanes) + cross-wave base: 3 barriers, exact
    int ws = v;
#pragma unroll
    for (int m = 1; m < 64; m <<= 1) {
        int up = __shfl_up(ws, m, 64);
        if (lane >= m) ws += up;
    }
    if (lane == 63) wsum[wave] = ws;
    __syncthreads();
    if (t < 16) {
        int x = wsum[t];
#pragma unroll
        for (int m = 1; m < 16; m <<= 1) {
            int up = __shfl_up(x, m, 16);
            if ((t & 15) >= m) x += up;
        }
        wsum[t] = x;
    }
    __syncthreads();
    int incl = ws + (wave ? wsum[wave - 1] : 0);
    lrow[t] = incl;                    // inclusive scan of lhist
    __syncthreads();
    if (t < BG) {
        int g = b * BG + t;
        if (g < n2) {
            row[g] = start + lrow[8 * t] - lhist[8 * t];
            int d = 0;
#pragma unroll
            for (int i = 0; i < 8; i++) d += lhist[8 * t + i];
            deg[g] = d;
        }
    }
    __syncthreads();
    lhist[t] = incl - v;               // slab-relative write cursor
    __syncthreads();
    for (int j = t * 4; j < cnt4; j += 4096) {
        int4 p = *(const int4*)(part + start + j);
        int pos;
        pos = atomicAdd(&lhist[key(p.x)], 1); slab[pos] = p.x >> 8;
        pos = atomicAdd(&lhist[key(p.y)], 1); slab[pos] = p.y >> 8;
        pos = atomicAdd(&lhist[key(p.z)], 1); slab[pos] = p.z >> 8;
        pos = atomicAdd(&lhist[key(p.w)], 1); slab[pos] = p.w >> 8;
    }
    for (int j = cnt4 + t; j < cnt; j += 1024) {
        int p = part[start + j];
        int pos = atomicAdd(&lhist[key(p)], 1);
        slab[pos] = p >> 8;
    }
    __syncthreads();
    {
        int ge = incl, gs = ge - v;    // this key's slab segment
        for (int i = gs + 1; i < ge; i++) {
            int x = slab[i], j2 = i - 1;
            while (j2 >= gs && slab[j2] > x) { slab[j2 + 1] = slab[j2]; j2--; }
            slab[j2 + 1] = x;
        }
    }
    __syncthreads();
    for (int j = t * 4; j < cnt4; j += 4096)
        *(int4*)(csr + start + j) = *(const int4*)(slab + j);
    for (int j = cnt4 + t; j < cnt; j += 1024) csr[start + j] = slab[j];
}

// ================= aggregates: single-half blocks, INTERLEAVED mapping =======
// half = blockIdx.x & 1 (measured-best: keeps both halves' src-sweeps
// temporally aligned). Gather = r1-proven 16-edge chunks, depth-3.

__device__ __forceinline__ void gather_body(
        const int* __restrict__ csr, int start, int cnt, float sd,
        const float* __restrict__ ss, const __half* __restrict__ hh,
        int l16, int slot, int fl8, int waveBase,
        float* acc, float& denomp) {
    int c16 = min(16, cnt);
    int sj = (l16 < c16) ? csr[start + l16] : 0;
    float wj = (l16 < c16) ? __expf(lrelu(ss[sj] + sd)) : 0.f;

    for (int base = 0; base < cnt; base += 16) {
        int nb2 = base + 16;
        int sjn = 0; float svn = 0.f; int c16n = cnt - nb2;
        if (nb2 < cnt) {
            sjn = (l16 < c16n) ? csr[start + nb2 + l16] : 0;
            svn = (l16 < c16n) ? ss[sjn] : 0.f;
        }
        denomp += wj;
        int nq = (min(16, cnt - base) + 1) >> 1;
        float w0 = __shfl(wj, waveBase + slot, 64);
        int s0 = __shfl(sj, waveBase + slot, 64);
        int4 r0 = *(const int4*)(hh + (size_t)s0 * ND + fl8);
        if (nq > 1) {
            float w1 = __shfl(wj, waveBase + 2 + slot, 64);
            int s1 = __shfl(sj, waveBase + 2 + slot, 64);
            int4 r1 = *(const int4*)(hh + (size_t)s1 * ND + fl8);
            for (int c = 2; c < nq; c++) {
                float w2 = __shfl(wj, waveBase + c * 2 + slot, 64);
                int s2 = __shfl(sj, waveBase + c * 2 + slot, 64);
                int4 r2 = *(const int4*)(hh + (size_t)s2 * ND + fl8);
                fma8(acc, w0, r0);
                w0 = w1; r0 = r1;
                w1 = w2; r1 = r2;
            }
            fma8(acc, w0, r0);
            fma8(acc, w1, r1);
        } else {
            fma8(acc, w0, r0);
        }
        if (nb2 < cnt) {
            wj = (l16 < c16n) ? __expf(lrelu(svn + sd)) : 0.f;
            sj = sjn;
        }
    }
}

// ---- layer-1 aggregate: relu'd per-half features (fp16) + first-hop logit ----
__global__ void agg1_h(const int* __restrict__ csr, const int* __restrict__ row,
                       const int* __restrict__ deg, const float* __restrict__ ss1,
                       const float* __restrict__ sd1, const __half* __restrict__ h16a,
                       const float* __restrict__ bA, const float* __restrict__ bB,
                       const float* __restrict__ fha,
                       __half* __restrict__ h1, float* __restrict__ plog, int N) {
    int half = blockIdx.x & 1;
    int wave = threadIdx.x >> 6;
    int lane = threadIdx.x & 63;
    int sub  = lane >> 4;
    int l16  = lane & 15;
    int slot = l16 >> 3;
    int fl8  = (l16 & 7) * 8;
    int node = ((blockIdx.x >> 1) * 4 + wave) * 4 + sub;
    bool valid = node < N;
    int g = half * N + node;
    const float* bias = half ? bB : bA;
    const float* ss = ss1 + (size_t)half * N;
    const __half* hh = h16a + (size_t)half * N * ND;
    const float* fhah = fha + half * ND;

    int start = valid ? row[g] : 0;
    int cnt   = valid ? deg[g] : 0;
    float sd  = valid ? sd1[g] : 0.f;
    float wself = valid ? __expf(lrelu(ss[node] + sd)) : 0.f;

    float acc[8] = {0.f, 0.f, 0.f, 0.f, 0.f, 0.f, 0.f, 0.f};
    float denomp = 0.f;
    gather_body(csr, start, cnt, sd, ss, hh, l16, slot, fl8, sub << 4, acc, denomp);

#pragma unroll
    for (int i = 0; i < 8; i++) acc[i] += __shfl_xor(acc[i], 8, 64);
#pragma unroll
    for (int m = 1; m <= 8; m <<= 1) denomp += __shfl_xor(denomp, m, 64);
    float denom = denomp + wself;

    if (!valid || slot != 0) return;
    int4 rawS = *(const int4*)(hh + (size_t)node * ND + fl8);
    union { int4 i; __half h[8]; } us;
    us.i = rawS;
    float v[8];
#pragma unroll
    for (int i = 0; i < 8; i++)
        v[i] = fmaxf((acc[i] + wself * __half2float(us.h[i])) / denom + bias[fl8 + i], 0.f);
    union { int4 i; __half h[8]; } uo;
#pragma unroll
    for (int i = 0; i < 8; i++) uo.h[i] = __float2half(v[i]);
    *(int4*)&h1[(size_t)g * ND + fl8] = uo.i;
    // first-hop attention logit: dot(fha[half], v) over the 8 active lanes
    float p = 0.f;
#pragma unroll
    for (int i = 0; i < 8; i++) p = fmaf(fhah[fl8 + i], v[i], p);
    p += __shfl_xor(p, 1, 64);
    p += __shfl_xor(p, 2, 64);
    p += __shfl_xor(p, 4, 64);
    if (l16 == 0) plog[g] = p;
}

// ---- layer-2 gemm with in-register softmax combine; emits edge scores AND
// the per-node scalar dots ta = att·h2, tm = mlpw·h2 (h2 itself never stored:
// agg2 is linear in h2, so only these scalars are ever needed downstream) ----
__global__ void __launch_bounds__(512) gemm2_combine(
        const __half* __restrict__ h1, const float* __restrict__ plog,
        const float* __restrict__ W2A, const float* __restrict__ W2B,
        const float* __restrict__ as2A, const float* __restrict__ ad2A,
        const float* __restrict__ as2B, const float* __restrict__ ad2B,
        const float* __restrict__ attw, const float* __restrict__ mlpw,
        float* __restrict__ ssrc2, float* __restrict__ sdst2,
        float* __restrict__ ta, float* __restrict__ tm, int N) {
    __shared__ float xs[16][ND];
    int t = threadIdx.x;
    int n0 = blockIdx.x * 16;
    if (t < 256) {
        int r = t >> 4, c = (t & 15) * 4;
        int n = n0 + r;
        float4 f = make_float4(0.f, 0.f, 0.f, 0.f);
        if (n < N) {
            union { int2 i; __half h[4]; } uI, uP;
            uI.i = *(const int2*)&h1[(size_t)n * ND + c];
            uP.i = *(const int2*)&h1[((size_t)N + n) * ND + c];
            float p0 = plog[n], p1 = plog[N + n];
            float mx = fmaxf(p0, p1);
            float e0 = __expf(p0 - mx), e1 = __expf(p1 - mx);
            float inv = 1.f / (e0 + e1);
            e0 *= inv; e1 *= inv;
            f.x = e0 * __half2float(uI.h[0]) + e1 * __half2float(uP.h[0]);
            f.y = e0 * __half2float(uI.h[1]) + e1 * __half2float(uP.h[1]);
            f.z = e0 * __half2float(uI.h[2]) + e1 * __half2float(uP.h[2]);
            f.w = e0 * __half2float(uI.h[3]) + e1 * __half2float(uP.h[3]);
        }
        *(float4*)&xs[r][c] = f;
    }
    __syncthreads();
    int wave = t >> 6, lane = t & 63;
    int half = wave >> 2;              // waves 0-3: half I, 4-7: half P
    int nb0 = (wave & 3) * 4;          // 4 nodes per wave
    const float* W  = half ? W2B : W2A;
    const float* av_ = half ? as2B : as2A;
    const float* dv_ = half ? ad2B : ad2A;
    const float* awh = attw + half * ND;

    float4 acc = {0.f, 0.f, 0.f, 0.f};
#pragma unroll
    for (int k = 0; k < ND; k++) {
        float wv = W[k * ND + lane];
        acc.x = fmaf(xs[nb0 + 0][k], wv, acc.x);
        acc.y = fmaf(xs[nb0 + 1][k], wv, acc.y);
        acc.z = fmaf(xs[nb0 + 2][k], wv, acc.z);
        acc.w = fmaf(xs[nb0 + 3][k], wv, acc.w);
    }
    float av = av_[lane], dv = dv_[lane];
    float aw = awh[lane], mw = mlpw[lane];
    float s1x = wave_sum(acc.x * av), s2x = wave_sum(acc.x * dv);
    float s1y = wave_sum(acc.y * av), s2y = wave_sum(acc.y * dv);
    float s1z = wave_sum(acc.z * av), s2z = wave_sum(acc.z * dv);
    float s1w = wave_sum(acc.w * av), s2w = wave_sum(acc.w * dv);
    float tax = wave_sum(acc.x * aw), tmx = wave_sum(acc.x * mw);
    float tay = wave_sum(acc.y * aw), tmy = wave_sum(acc.y * mw);
    float taz = wave_sum(acc.z * aw), tmz = wave_sum(acc.z * mw);
    float taw = wave_sum(acc.w * aw), tmw = wave_sum(acc.w * mw);

    int node = n0 + nb0;
    int g0 = half * N + node;
    if (lane == 0) {
        if (node + 0 < N) { ssrc2[g0 + 0] = s1x; sdst2[g0 + 0] = s2x; ta[g0 + 0] = tax; tm[g0 + 0] = tmx; }
        if (node + 1 < N) { ssrc2[g0 + 1] = s1y; sdst2[g0 + 1] = s2y; ta[g0 + 1] = tay; tm[g0 + 1] = tmy; }
        if (node + 2 < N) { ssrc2[g0 + 2] = s1z; sdst2[g0 + 2] = s2z; ta[g0 + 2] = taz; tm[g0 + 2] = tmz; }
        if (node + 3 < N) { ssrc2[g0 + 3] = s1w; sdst2[g0 + 3] = s2w; ta[g0 + 3] = taw; tm[g0 + 3] = tmw; }
    }
}

// ---- layer-2 aggregate, SCALARIZED: per edge gathers only 3 scalars
// (ss, ta, tm — tables 400 KB each, L2-resident) instead of a 128 B row.
// pa = (Σ w ta + wself ta_d)/denom + att·b2 ; pm likewise with mlpw. ----
__global__ void agg2_scal(const int* __restrict__ csr, const int* __restrict__ row,
                          const int* __restrict__ deg, const float* __restrict__ ss2,
                          const float* __restrict__ sd2,
                          const float* __restrict__ ta, const float* __restrict__ tm,
                          const float* __restrict__ b2A, const float* __restrict__ b2B,
                          const float* __restrict__ attw, const float* __restrict__ mlpw,
                          float* __restrict__ satt, float* __restrict__ mmlp, int N) {
    int half = blockIdx.x & 1;
    int wave = threadIdx.x >> 6;
    int lane = threadIdx.x & 63;
    int sub  = lane >> 4;
    int l16  = lane & 15;
    int node = ((blockIdx.x >> 1) * 4 + wave) * 4 + sub;
    bool valid = node < N;
    int g = half * N + node;
    const float* ss = ss2 + (size_t)half * N;
    const float* tah = ta + (size_t)half * N;
    const float* tmh = tm + (size_t)half * N;
    const float* bh = half ? b2B : b2A;
    const float* awh = attw + half * ND;

    // per-half constant bias dots (wave-uniform, fixed shuffle tree)
    float attb = wave_sum(awh[lane] * bh[lane]);
    float mb   = wave_sum(mlpw[lane] * bh[lane]);

    int start = valid ? row[g] : 0;
    int cnt   = valid ? deg[g] : 0;
    float sd  = valid ? sd2[g] : 0.f;

    // lane l16 takes neighbors j ≡ l16 (mod 16), in csr order: deterministic
    float aw = 0.f, aa = 0.f, am = 0.f;
    for (int j = l16; j < cnt; j += 16) {
        int s = csr[start + j];
        float w = __expf(lrelu(ss[s] + sd));
        aw += w;
        aa = fmaf(w, tah[s], aa);
        am = fmaf(w, tmh[s], am);
    }
#pragma unroll
    for (int m = 1; m <= 8; m <<= 1) {
        aw += __shfl_xor(aw, m, 64);
        aa += __shfl_xor(aa, m, 64);
        am += __shfl_xor(am, m, 64);
    }
    if (!valid || l16 != 0) return;
    float wself = __expf(lrelu(ss[node] + sd));
    float denom = aw + wself;
    satt[g] = (aa + wself * tah[node]) / denom + attb;
    mmlp[g] = (am + wself * tmh[node]) / denom + mb;
}

// ---- final: per-node branch softmax over the two scalar dots ----
__global__ void final_combine(const float* __restrict__ satt, const float* __restrict__ mmlp,
                              const float* __restrict__ mlpb, float* __restrict__ out, int N) {
    int i = blockIdx.x * blockDim.x + threadIdx.x;
    if (i >= N) return;
    float s0 = satt[i], s1 = satt[N + i];
    float m = fmaxf(s0, s1);
    float e0 = __expf(s0 - m), e1 = __expf(s1 - m);
    out[i] = (e0 * mmlp[i] + e1 * mmlp[N + i]) / (e0 + e1) + mlpb[0];
}

extern "C" void kernel_launch(void* const* d_in, const int* in_sizes, int n_in,
                              void* d_out, int out_size, void* d_ws, size_t ws_size,
                              hipStream_t stream) {
    const int N = in_sizes[0] / ND;   // 50000
    const int E = in_sizes[2] / 2;    // 1600000

    const float* x_ind = (const float*)d_in[0];
    const float* x_pos = (const float*)d_in[1];
    const int*   e_ind = (const int*)d_in[2];
    const int*   e_pos = (const int*)d_in[3];
    const float* w1i = (const float*)d_in[4];
    const float* as1i = (const float*)d_in[5];
    const float* ad1i = (const float*)d_in[6];
    const float* b1i = (const float*)d_in[7];
    const float* w2i = (const float*)d_in[8];
    const float* as2i = (const float*)d_in[9];
    const float* ad2i = (const float*)d_in[10];
    const float* b2i = (const float*)d_in[11];
    const float* w1p = (const float*)d_in[12];
    const float* as1p = (const float*)d_in[13];
    const float* ad1p = (const float*)d_in[14];
    const float* b1p = (const float*)d_in[15];
    const float* w2p = (const float*)d_in[16];
    const float* as2p = (const float*)d_in[17];
    const float* ad2p = (const float*)d_in[18];
    const float* b2p = (const float*)d_in[19];
    const float* fha = (const float*)d_in[20];
    const float* attw = (const float*)d_in[21];
    const float* mlpw = (const float*)d_in[22];
    const float* mlpb = (const float*)d_in[23];

    char* ws = (char*)d_ws;
    size_t off = 0;
    auto alloc = [&](size_t elems) { void* p = ws + off; off += elems * 4; return p; };

    const int n2 = 2 * N;
    const int nb = (n2 + BG - 1) / BG;             // 782

    __half* h16a = (__half*)alloc((size_t)n2 * ND / 2);  // layer-1 gemm fp16, 12.8 MB
    float* ssrc1 = (float*)alloc(n2);
    float* sdst1 = (float*)alloc(n2);
    float* ssrc2 = (float*)alloc(n2);
    float* sdst2 = (float*)alloc(n2);
    float* plog  = (float*)alloc(n2);
    float* satt  = (float*)alloc(n2);
    float* mmlp  = (float*)alloc(n2);
    float* tad   = (float*)alloc(n2);
    float* tmd   = (float*)alloc(n2);
    int* deg    = (int*)alloc(n2);
    int* rowi   = (int*)alloc(n2);
    int* csr    = (int*)alloc((size_t)nb * CAP);        // 14.4 MB slabs
    int* bcursor= (int*)alloc(MAXB);
    int* part   = (int*)alloc((size_t)nb * CAP);        // 14.4 MB
    // h1 aliases part (12.8 <= 14.4 MB): part is dead after bucket_build,
    // before agg1_h writes h1.
    __half* h1 = (__half*)part;

    const int partBlocks  = (2 * E + PCH - 1) / PCH;        // 196
    const int gemm1Blocks = 2 * ((N + 63) / 64);            // 1564
    const int aggBlocks   = 2 * ((N + 15) / 16);            // 6250 (interleaved halves)
    const int gemm2Blocks = (N + 15) / 16;                  // 3125
    const int finBlocks   = (N + 255) / 256;                // 196

    // ---- CSR build overlapped with layer-1 gemm (independent work) ----
    hipMemsetAsync(bcursor, 0, MAXB * sizeof(int), stream);   // relative cursors
    part_gemm<<<partBlocks + gemm1Blocks, 1024, 0, stream>>>(
        e_ind, e_pos, bcursor, part,
        x_ind, x_pos, w1i, w1p, as1i, ad1i, as1p, ad1p,
        h16a, ssrc1, sdst1, N, E, nb, partBlocks);
    bucket_build<<<nb, 1024, 0, stream>>>(part, bcursor, rowi, deg, csr, n2, N);

    // ---- layer-1 aggregate (interleaved halves) -> fp16 halves + logits ----
    agg1_h<<<aggBlocks, 256, 0, stream>>>(
        csr, rowi, deg, ssrc1, sdst1, h16a, b1i, b1p, fha, h1, plog, N);

    // ---- layer-2 gemm with in-register first-hop combine -> scores + dots ----
    gemm2_combine<<<gemm2Blocks, 512, 0, stream>>>(
        h1, plog, w2i, w2p, as2i, ad2i, as2p, ad2p,
        attw, mlpw, ssrc2, sdst2, tad, tmd, N);

    // ---- layer-2 aggregate, scalarized (3×4 B per edge instead of 128 B) ----
    agg2_scal<<<aggBlocks, 256, 0, stream>>>(
        csr, rowi, deg, ssrc2, sdst2, tad, tmd, b2i, b2p,
        attw, mlpw, satt, mmlp, N);

    // ---- final branch softmax + bias ----
    final_combine<<<finBlocks, 256, 0, stream>>>(satt, mmlp, mlpb, (float*)d_out, N);
}

// Round 11
// 304.462 us; speedup vs baseline: 1.0768x; 1.0768x over previous
//
#include <hip/hip_runtime.h>
#include <hip/hip_fp16.h>

#define ND 64
#define BG 128        // dst ids per bucket
#define MAXB 1024     // max buckets (LDS sizing); nb = ceil(2N/BG) = 782
#define PCH 16384     // edges per partition chunk: 196 part-blocks
#define CAP 4608      // per-bucket slab capacity; lambda=4096, sigma~64 -> 8-sigma margin

__device__ __forceinline__ float lrelu(float x) { return x > 0.f ? x : 0.2f * x; }

__device__ __forceinline__ float wave_sum(float v) {
#pragma unroll
    for (int m = 32; m > 0; m >>= 1) v += __shfl_xor(v, m, 64);
    return v;
}

// 8 fp16 x fp32 fused into 8 fp32 accumulators (v_fma_mix_f32 form)
__device__ __forceinline__ void fma8(float* acc, float w, int4 raw) {
    union { int4 i; __half h[8]; } u;
    u.i = raw;
#pragma unroll
    for (int i = 0; i < 8; i++) acc[i] = fmaf(w, __half2float(u.h[i]), acc[i]);
}

// ---------------- bucketed CSR build (fixed-capacity slabs) ----------------
// bcursor is zeroed via hipMemsetAsync; cursors are RELATIVE (run offset
// within bucket b's slab at b*CAP).

__device__ void partition_body(int* hist, int* lcur,
                               const int* __restrict__ eI, const int* __restrict__ eP,
                               int* __restrict__ bcursor, int* __restrict__ part,
                               int N, int E, int nb) {
    int t = threadIdx.x;
    int total = 2 * E;
    int chunkBase = blockIdx.x * PCH;
    int cnt = min(PCH, total - chunkBase);
    if (t < nb) hist[t] = 0;
    __syncthreads();

    if (cnt == PCH) {
        int pk[16];
        unsigned bkp[8];
#pragma unroll
        for (int it = 0; it < 4; it++) {
            int i = t * 4 + it * 4096;
            int e = chunkBase + i;
            int sv[4], dv[4];
            if (e + 3 < E) {
                int4 a = *(const int4*)(eI + e);
                int4 b = *(const int4*)(eI + E + e);
                sv[0] = a.x; sv[1] = a.y; sv[2] = a.z; sv[3] = a.w;
                dv[0] = b.x; dv[1] = b.y; dv[2] = b.z; dv[3] = b.w;
            } else if (e >= E) {
                int4 a = *(const int4*)(eP + (e - E));
                int4 b = *(const int4*)(eP + E + (e - E));
                sv[0] = a.x; sv[1] = a.y; sv[2] = a.z; sv[3] = a.w;
                dv[0] = b.x + N; dv[1] = b.y + N; dv[2] = b.z + N; dv[3] = b.w + N;
            } else {
#pragma unroll
                for (int k = 0; k < 4; k++) {
                    int ee = e + k;
                    if (ee < E) { sv[k] = eI[ee]; dv[k] = eI[E + ee]; }
                    else        { sv[k] = eP[ee - E]; dv[k] = N + eP[E + ee - E]; }
                }
            }
#pragma unroll
            for (int k = 0; k < 4; k++) {
                int j = it * 4 + k;
                int bk = dv[k] >> 7;
                pk[j] = (sv[k] << 8) | (dv[k] & 255);
                atomicAdd(&hist[bk], 1);
                if ((j & 1) == 0) bkp[j >> 1] = (unsigned)bk;
                else bkp[j >> 1] |= (unsigned)bk << 16;
            }
        }
        __syncthreads();
        if (t < nb) lcur[t] = t * CAP + (hist[t] ? atomicAdd(&bcursor[t], hist[t]) : 0);
        __syncthreads();
#pragma unroll
        for (int j = 0; j < 16; j++) {
            int bk = (bkp[j >> 1] >> ((j & 1) * 16)) & 0xffff;
            int pos = atomicAdd(&lcur[bk], 1);
            part[pos] = pk[j];
        }
        return;
    }

    // slow path (tail chunk only)
    int cnt4 = cnt & ~3;
    for (int i = t * 4; i < cnt4; i += 4096) {
        int e = chunkBase + i;
        int4 d; int base;
        if (e + 3 < E)   { d = *(const int4*)(eI + E + e); base = 0; }
        else if (e >= E) { d = *(const int4*)(eP + E + (e - E)); base = N; }
        else {
            int tmp[4];
#pragma unroll
            for (int k = 0; k < 4; k++) {
                int ee = e + k;
                tmp[k] = (ee < E) ? eI[E + ee] : N + eP[E + ee - E];
            }
            d = make_int4(tmp[0], tmp[1], tmp[2], tmp[3]); base = 0;
        }
        atomicAdd(&hist[(base + d.x) >> 7], 1);
        atomicAdd(&hist[(base + d.y) >> 7], 1);
        atomicAdd(&hist[(base + d.z) >> 7], 1);
        atomicAdd(&hist[(base + d.w) >> 7], 1);
    }
    for (int i = cnt4 + t; i < cnt; i += 1024) {
        int e = chunkBase + i;
        int idx = (e < E) ? eI[E + e] : N + eP[E + (e - E)];
        atomicAdd(&hist[idx >> 7], 1);
    }
    __syncthreads();
    if (t < nb) lcur[t] = t * CAP + (hist[t] ? atomicAdd(&bcursor[t], hist[t]) : 0);
    __syncthreads();
    for (int i = t; i < cnt; i += 1024) {
        int e = chunkBase + i;
        int s, idx;
        if (e < E) { s = eI[e]; idx = eI[E + e]; }
        else       { s = eP[e - E]; idx = N + eP[E + (e - E)]; }
        int pos = atomicAdd(&lcur[idx >> 7], 1);
        part[pos] = (s << 8) | (idx & 255);
    }
}

// ---- gemm body: h(fp16) = x @ W + score dots; 16 waves/block, 4 nodes/wave ----
__device__ void gemm_body(float* xsAll, int gb,
                          const float* __restrict__ xA, const float* __restrict__ xB,
                          const float* __restrict__ WA, const float* __restrict__ WB,
                          const float* __restrict__ asA, const float* __restrict__ adA,
                          const float* __restrict__ asB, const float* __restrict__ adB,
                          __half* __restrict__ h16, float* __restrict__ ssrc,
                          float* __restrict__ sdst, int N) {
    int half = gb & 1;
    int blk = gb >> 1;
    int wave = threadIdx.x >> 6;
    int lane = threadIdx.x & 63;
    const float* x  = half ? xB : xA;
    const float* W  = half ? WB : WA;
    const float* av_ = half ? asB : asA;
    const float* dv_ = half ? adB : adA;
    int nodeBase = (blk * 16 + wave) * 4;      // within half
    float* xs = xsAll + wave * (4 * ND);

    if (nodeBase + 3 < N) {
        *(float4*)&xs[lane * 4] = *(const float4*)&x[(size_t)nodeBase * ND + lane * 4];
    } else if (nodeBase < N) {
#pragma unroll
        for (int i = 0; i < 4; i++) {
            int gi = nodeBase * ND + lane * 4 + i;
            xs[lane * 4 + i] = (gi < N * ND) ? x[gi] : 0.f;
        }
    }
    __syncthreads();
    if (nodeBase >= N) return;

    float4 acc = {0.f, 0.f, 0.f, 0.f};
#pragma unroll
    for (int k = 0; k < ND; k++) {
        float wv = W[k * ND + lane];
        acc.x = fmaf(xs[0 * ND + k], wv, acc.x);
        acc.y = fmaf(xs[1 * ND + k], wv, acc.y);
        acc.z = fmaf(xs[2 * ND + k], wv, acc.z);
        acc.w = fmaf(xs[3 * ND + k], wv, acc.w);
    }
    float av = av_[lane], dv = dv_[lane];
    float s1x = wave_sum(acc.x * av), s2x = wave_sum(acc.x * dv);
    float s1y = wave_sum(acc.y * av), s2y = wave_sum(acc.y * dv);
    float s1z = wave_sum(acc.z * av), s2z = wave_sum(acc.z * dv);
    float s1w = wave_sum(acc.w * av), s2w = wave_sum(acc.w * dv);

    int g0 = half * N + nodeBase;
    h16[(size_t)(g0 + 0) * ND + lane] = __float2half(acc.x);
    if (nodeBase + 1 < N) h16[(size_t)(g0 + 1) * ND + lane] = __float2half(acc.y);
    if (nodeBase + 2 < N) h16[(size_t)(g0 + 2) * ND + lane] = __float2half(acc.z);
    if (nodeBase + 3 < N) h16[(size_t)(g0 + 3) * ND + lane] = __float2half(acc.w);
    if (lane == 0) {
        ssrc[g0] = s1x; sdst[g0] = s2x;
        if (nodeBase + 1 < N) { ssrc[g0 + 1] = s1y; sdst[g0 + 1] = s2y; }
        if (nodeBase + 2 < N) { ssrc[g0 + 2] = s1z; sdst[g0 + 2] = s2z; }
        if (nodeBase + 3 < N) { ssrc[g0 + 3] = s1w; sdst[g0 + 3] = s2w; }
    }
}

// ---- fused: partition (blocks < partBlocks) | layer-1 gemm (the rest) ----
__global__ void __launch_bounds__(1024) part_gemm(
        const int* __restrict__ eI, const int* __restrict__ eP,
        int* __restrict__ bcursor, int* __restrict__ part,
        const float* __restrict__ xA, const float* __restrict__ xB,
        const float* __restrict__ WA, const float* __restrict__ WB,
        const float* __restrict__ asA, const float* __restrict__ adA,
        const float* __restrict__ asB, const float* __restrict__ adB,
        __half* __restrict__ h16, float* __restrict__ ssrc, float* __restrict__ sdst,
        int N, int E, int nb, int partBlocks) {
    __shared__ int smem[16 * 4 * ND];   // 16 KB
    if (blockIdx.x < partBlocks) {
        partition_body(smem, smem + MAXB, eI, eP, bcursor, part, N, E, nb);
    } else {
        gemm_body((float*)smem, blockIdx.x - partBlocks,
                  xA, xB, WA, WB, asA, adA, asB, adB, h16, ssrc, sdst, N);
    }
}

// one block (1024 thr) per bucket: hist + wave-shfl scan -> row/deg, LDS
// scatter + per-key insertion sort by src (deterministic csr), int4 copy-out.
__global__ void bucket_build(const int* __restrict__ part, const int* __restrict__ bcursor,
                             int* __restrict__ row, int* __restrict__ deg,
                             int* __restrict__ csr, int n2, int N) {
    __shared__ int lhist[BG * 8];
    __shared__ int lrow[BG * 8];
    __shared__ int slab[CAP];
    __shared__ int wsum[16];
    int b = blockIdx.x, t = threadIdx.x;
    int lane = t & 63, wave = t >> 6;
    int start = b * CAP;
    int cnt = min(bcursor[b], CAP);
    int cnt4 = cnt & ~3;
    int t1 = (N * 1) >> 3, t2 = (N * 2) >> 3, t3 = (N * 3) >> 3, t4 = (N * 4) >> 3;
    int t5 = (N * 5) >> 3, t6 = (N * 6) >> 3, t7 = (N * 7) >> 3;
    auto key = [&](int p) {
        int s = p >> 8;
        int o = (s >= t1) + (s >= t2) + (s >= t3) + (s >= t4)
              + (s >= t5) + (s >= t6) + (s >= t7);
        return ((p & 127) << 3) | o;
    };
    lhist[t] = 0;
    __syncthreads();
    for (int j = t * 4; j < cnt4; j += 4096) {
        int4 p = *(const int4*)(part + start + j);
        atomicAdd(&lhist[key(p.x)], 1);
        atomicAdd(&lhist[key(p.y)], 1);
        atomicAdd(&lhist[key(p.z)], 1);
        atomicAdd(&lhist[key(p.w)], 1);
    }
    for (int j = cnt4 + t; j < cnt; j += 1024) atomicAdd(&lhist[key(part[start + j])], 1);
    __syncthreads();
    int v = lhist[t];
    // wave-level inclusive scan (64 lanes) + cross-wave base: 3 barriers, exact
    int ws = v;
#pragma unroll
    for (int m = 1; m < 64; m <<= 1) {
        int up = __shfl_up(ws, m, 64);
        if (lane >= m) ws += up;
    }
    if (lane == 63) wsum[wave] = ws;
    __syncthreads();
    if (t < 16) {
        int x = wsum[t];
#pragma unroll
        for (int m = 1; m < 16; m <<= 1) {
            int up = __shfl_up(x, m, 16);
            if ((t & 15) >= m) x += up;
        }
        wsum[t] = x;
    }
    __syncthreads();
    int incl = ws + (wave ? wsum[wave - 1] : 0);
    lrow[t] = incl;                    // inclusive scan of lhist
    __syncthreads();
    if (t < BG) {
        int g = b * BG + t;
        if (g < n2) {
            row[g] = start + lrow[8 * t] - lhist[8 * t];
            int d = 0;
#pragma unroll
            for (int i = 0; i < 8; i++) d += lhist[8 * t + i];
            deg[g] = d;
        }
    }
    __syncthreads();
    lhist[t] = incl - v;               // slab-relative write cursor
    __syncthreads();
    for (int j = t * 4; j < cnt4; j += 4096) {
        int4 p = *(const int4*)(part + start + j);
        int pos;
        pos = atomicAdd(&lhist[key(p.x)], 1); slab[pos] = p.x >> 8;
        pos = atomicAdd(&lhist[key(p.y)], 1); slab[pos] = p.y >> 8;
        pos = atomicAdd(&lhist[key(p.z)], 1); slab[pos] = p.z >> 8;
        pos = atomicAdd(&lhist[key(p.w)], 1); slab[pos] = p.w >> 8;
    }
    for (int j = cnt4 + t; j < cnt; j += 1024) {
        int p = part[start + j];
        int pos = atomicAdd(&lhist[key(p)], 1);
        slab[pos] = p >> 8;
    }
    __syncthreads();
    {
        int ge = incl, gs = ge - v;    // this key's slab segment
        for (int i = gs + 1; i < ge; i++) {
            int x = slab[i], j2 = i - 1;
            while (j2 >= gs && slab[j2] > x) { slab[j2 + 1] = slab[j2]; j2--; }
            slab[j2 + 1] = x;
        }
    }
    __syncthreads();
    for (int j = t * 4; j < cnt4; j += 4096)
        *(int4*)(csr + start + j) = *(const int4*)(slab + j);
    for (int j = cnt4 + t; j < cnt; j += 1024) csr[start + j] = slab[j];
}

// ================= aggregates: single-half blocks, INTERLEAVED mapping =======
// half = blockIdx.x & 1 (measured-best: keeps both halves' src-sweeps
// temporally aligned). Gather = r1-proven 16-edge chunks, depth-3.

__device__ __forceinline__ void gather_body(
        const int* __restrict__ csr, int start, int cnt, float sd,
        const float* __restrict__ ss, const __half* __restrict__ hh,
        int l16, int slot, int fl8, int waveBase,
        float* acc, float& denomp) {
    int c16 = min(16, cnt);
    int sj = (l16 < c16) ? csr[start + l16] : 0;
    float wj = (l16 < c16) ? __expf(lrelu(ss[sj] + sd)) : 0.f;

    for (int base = 0; base < cnt; base += 16) {
        int nb2 = base + 16;
        int sjn = 0; float svn = 0.f; int c16n = cnt - nb2;
        if (nb2 < cnt) {
            sjn = (l16 < c16n) ? csr[start + nb2 + l16] : 0;
            svn = (l16 < c16n) ? ss[sjn] : 0.f;
        }
        denomp += wj;
        int nq = (min(16, cnt - base) + 1) >> 1;
        float w0 = __shfl(wj, waveBase + slot, 64);
        int s0 = __shfl(sj, waveBase + slot, 64);
        int4 r0 = *(const int4*)(hh + (size_t)s0 * ND + fl8);
        if (nq > 1) {
            float w1 = __shfl(wj, waveBase + 2 + slot, 64);
            int s1 = __shfl(sj, waveBase + 2 + slot, 64);
            int4 r1 = *(const int4*)(hh + (size_t)s1 * ND + fl8);
            for (int c = 2; c < nq; c++) {
                float w2 = __shfl(wj, waveBase + c * 2 + slot, 64);
                int s2 = __shfl(sj, waveBase + c * 2 + slot, 64);
                int4 r2 = *(const int4*)(hh + (size_t)s2 * ND + fl8);
                fma8(acc, w0, r0);
                w0 = w1; r0 = r1;
                w1 = w2; r1 = r2;
            }
            fma8(acc, w0, r0);
            fma8(acc, w1, r1);
        } else {
            fma8(acc, w0, r0);
        }
        if (nb2 < cnt) {
            wj = (l16 < c16n) ? __expf(lrelu(svn + sd)) : 0.f;
            sj = sjn;
        }
    }
}

// ---- layer-1 aggregate: relu'd per-half features (fp16) + first-hop logit ----
__global__ void agg1_h(const int* __restrict__ csr, const int* __restrict__ row,
                       const int* __restrict__ deg, const float* __restrict__ ss1,
                       const float* __restrict__ sd1, const __half* __restrict__ h16a,
                       const float* __restrict__ bA, const float* __restrict__ bB,
                       const float* __restrict__ fha,
                       __half* __restrict__ h1, float* __restrict__ plog, int N) {
    int half = blockIdx.x & 1;
    int wave = threadIdx.x >> 6;
    int lane = threadIdx.x & 63;
    int sub  = lane >> 4;
    int l16  = lane & 15;
    int slot = l16 >> 3;
    int fl8  = (l16 & 7) * 8;
    int node = ((blockIdx.x >> 1) * 4 + wave) * 4 + sub;
    bool valid = node < N;
    int g = half * N + node;
    const float* bias = half ? bB : bA;
    const float* ss = ss1 + (size_t)half * N;
    const __half* hh = h16a + (size_t)half * N * ND;
    const float* fhah = fha + half * ND;

    int start = valid ? row[g] : 0;
    int cnt   = valid ? deg[g] : 0;
    float sd  = valid ? sd1[g] : 0.f;
    float wself = valid ? __expf(lrelu(ss[node] + sd)) : 0.f;

    float acc[8] = {0.f, 0.f, 0.f, 0.f, 0.f, 0.f, 0.f, 0.f};
    float denomp = 0.f;
    gather_body(csr, start, cnt, sd, ss, hh, l16, slot, fl8, sub << 4, acc, denomp);

#pragma unroll
    for (int i = 0; i < 8; i++) acc[i] += __shfl_xor(acc[i], 8, 64);
#pragma unroll
    for (int m = 1; m <= 8; m <<= 1) denomp += __shfl_xor(denomp, m, 64);
    float denom = denomp + wself;

    if (!valid || slot != 0) return;
    int4 rawS = *(const int4*)(hh + (size_t)node * ND + fl8);
    union { int4 i; __half h[8]; } us;
    us.i = rawS;
    float v[8];
#pragma unroll
    for (int i = 0; i < 8; i++)
        v[i] = fmaxf((acc[i] + wself * __half2float(us.h[i])) / denom + bias[fl8 + i], 0.f);
    union { int4 i; __half h[8]; } uo;
#pragma unroll
    for (int i = 0; i < 8; i++) uo.h[i] = __float2half(v[i]);
    *(int4*)&h1[(size_t)g * ND + fl8] = uo.i;
    // first-hop attention logit: dot(fha[half], v) over the 8 active lanes
    float p = 0.f;
#pragma unroll
    for (int i = 0; i < 8; i++) p = fmaf(fhah[fl8 + i], v[i], p);
    p += __shfl_xor(p, 1, 64);
    p += __shfl_xor(p, 2, 64);
    p += __shfl_xor(p, 4, 64);
    if (l16 == 0) plog[g] = p;
}

// ---- layer-2 gemm with in-register softmax combine; emits per-node PACKED
// float4 q2 = (ssrc2, att·h2, mlpw·h2, 0) + sdst2. h2 itself is never stored:
// agg2 is linear in h2, so only these scalars are needed downstream; packing
// them in ONE 16 B struct makes agg2's per-edge gather a single line-request ----
__global__ void __launch_bounds__(512) gemm2_combine(
        const __half* __restrict__ h1, const float* __restrict__ plog,
        const float* __restrict__ W2A, const float* __restrict__ W2B,
        const float* __restrict__ as2A, const float* __restrict__ ad2A,
        const float* __restrict__ as2B, const float* __restrict__ ad2B,
        const float* __restrict__ attw, const float* __restrict__ mlpw,
        float4* __restrict__ q2, float* __restrict__ sdst2, int N) {
    __shared__ float xs[16][ND];
    int t = threadIdx.x;
    int n0 = blockIdx.x * 16;
    if (t < 256) {
        int r = t >> 4, c = (t & 15) * 4;
        int n = n0 + r;
        float4 f = make_float4(0.f, 0.f, 0.f, 0.f);
        if (n < N) {
            union { int2 i; __half h[4]; } uI, uP;
            uI.i = *(const int2*)&h1[(size_t)n * ND + c];
            uP.i = *(const int2*)&h1[((size_t)N + n) * ND + c];
            float p0 = plog[n], p1 = plog[N + n];
            float mx = fmaxf(p0, p1);
            float e0 = __expf(p0 - mx), e1 = __expf(p1 - mx);
            float inv = 1.f / (e0 + e1);
            e0 *= inv; e1 *= inv;
            f.x = e0 * __half2float(uI.h[0]) + e1 * __half2float(uP.h[0]);
            f.y = e0 * __half2float(uI.h[1]) + e1 * __half2float(uP.h[1]);
            f.z = e0 * __half2float(uI.h[2]) + e1 * __half2float(uP.h[2]);
            f.w = e0 * __half2float(uI.h[3]) + e1 * __half2float(uP.h[3]);
        }
        *(float4*)&xs[r][c] = f;
    }
    __syncthreads();
    int wave = t >> 6, lane = t & 63;
    int half = wave >> 2;              // waves 0-3: half I, 4-7: half P
    int nb0 = (wave & 3) * 4;          // 4 nodes per wave
    const float* W  = half ? W2B : W2A;
    const float* av_ = half ? as2B : as2A;
    const float* dv_ = half ? ad2B : ad2A;
    const float* awh = attw + half * ND;

    float4 acc = {0.f, 0.f, 0.f, 0.f};
#pragma unroll
    for (int k = 0; k < ND; k++) {
        float wv = W[k * ND + lane];
        acc.x = fmaf(xs[nb0 + 0][k], wv, acc.x);
        acc.y = fmaf(xs[nb0 + 1][k], wv, acc.y);
        acc.z = fmaf(xs[nb0 + 2][k], wv, acc.z);
        acc.w = fmaf(xs[nb0 + 3][k], wv, acc.w);
    }
    float av = av_[lane], dv = dv_[lane];
    float aw = awh[lane], mw = mlpw[lane];
    float s1x = wave_sum(acc.x * av), s2x = wave_sum(acc.x * dv);
    float s1y = wave_sum(acc.y * av), s2y = wave_sum(acc.y * dv);
    float s1z = wave_sum(acc.z * av), s2z = wave_sum(acc.z * dv);
    float s1w = wave_sum(acc.w * av), s2w = wave_sum(acc.w * dv);
    float tax = wave_sum(acc.x * aw), tmx = wave_sum(acc.x * mw);
    float tay = wave_sum(acc.y * aw), tmy = wave_sum(acc.y * mw);
    float taz = wave_sum(acc.z * aw), tmz = wave_sum(acc.z * mw);
    float taw = wave_sum(acc.w * aw), tmw = wave_sum(acc.w * mw);

    int node = n0 + nb0;
    int g0 = half * N + node;
    if (lane == 0) {
        if (node + 0 < N) { q2[g0 + 0] = make_float4(s1x, tax, tmx, 0.f); sdst2[g0 + 0] = s2x; }
        if (node + 1 < N) { q2[g0 + 1] = make_float4(s1y, tay, tmy, 0.f); sdst2[g0 + 1] = s2y; }
        if (node + 2 < N) { q2[g0 + 2] = make_float4(s1z, taz, tmz, 0.f); sdst2[g0 + 2] = s2z; }
        if (node + 3 < N) { q2[g0 + 3] = make_float4(s1w, taw, tmw, 0.f); sdst2[g0 + 3] = s2w; }
    }
}

// ---- layer-2 aggregate, SCALARIZED + PACKED: one float4 load per edge
// (q2 table 1.6 MB, L2-resident) — 3x fewer L2 line-requests than r10's
// three separate 4 B gathers. pa = (Σ w·ta + wself·ta_d)/denom + att·b2. ----
__global__ void agg2_scal(const int* __restrict__ csr, const int* __restrict__ row,
                          const int* __restrict__ deg, const float4* __restrict__ q2,
                          const float* __restrict__ sd2,
                          const float* __restrict__ b2A, const float* __restrict__ b2B,
                          const float* __restrict__ attw, const float* __restrict__ mlpw,
                          float* __restrict__ satt, float* __restrict__ mmlp, int N) {
    int half = blockIdx.x & 1;
    int wave = threadIdx.x >> 6;
    int lane = threadIdx.x & 63;
    int sub  = lane >> 4;
    int l16  = lane & 15;
    int node = ((blockIdx.x >> 1) * 4 + wave) * 4 + sub;
    bool valid = node < N;
    int g = half * N + node;
    const float4* qh = q2 + (size_t)half * N;
    const float* bh = half ? b2B : b2A;
    const float* awh = attw + half * ND;

    // per-half constant bias dots (wave-uniform, fixed shuffle tree)
    float attb = wave_sum(awh[lane] * bh[lane]);
    float mb   = wave_sum(mlpw[lane] * bh[lane]);

    int start = valid ? row[g] : 0;
    int cnt   = valid ? deg[g] : 0;
    float sd  = valid ? sd2[g] : 0.f;

    // lane l16 takes neighbors j ≡ l16 (mod 16), in csr order: deterministic
    float aw = 0.f, aa = 0.f, am = 0.f;
    for (int j = l16; j < cnt; j += 16) {
        int s = csr[start + j];
        float4 q = qh[s];
        float w = __expf(lrelu(q.x + sd));
        aw += w;
        aa = fmaf(w, q.y, aa);
        am = fmaf(w, q.z, am);
    }
#pragma unroll
    for (int m = 1; m <= 8; m <<= 1) {
        aw += __shfl_xor(aw, m, 64);
        aa += __shfl_xor(aa, m, 64);
        am += __shfl_xor(am, m, 64);
    }
    if (!valid || l16 != 0) return;
    float4 qs = qh[node];
    float wself = __expf(lrelu(qs.x + sd));
    float denom = aw + wself;
    satt[g] = (aa + wself * qs.y) / denom + attb;
    mmlp[g] = (am + wself * qs.z) / denom + mb;
}

// ---- final: per-node branch softmax over the two scalar dots ----
__global__ void final_combine(const float* __restrict__ satt, const float* __restrict__ mmlp,
                              const float* __restrict__ mlpb, float* __restrict__ out, int N) {
    int i = blockIdx.x * blockDim.x + threadIdx.x;
    if (i >= N) return;
    float s0 = satt[i], s1 = satt[N + i];
    float m = fmaxf(s0, s1);
    float e0 = __expf(s0 - m), e1 = __expf(s1 - m);
    out[i] = (e0 * mmlp[i] + e1 * mmlp[N + i]) / (e0 + e1) + mlpb[0];
}

extern "C" void kernel_launch(void* const* d_in, const int* in_sizes, int n_in,
                              void* d_out, int out_size, void* d_ws, size_t ws_size,
                              hipStream_t stream) {
    const int N = in_sizes[0] / ND;   // 50000
    const int E = in_sizes[2] / 2;    // 1600000

    const float* x_ind = (const float*)d_in[0];
    const float* x_pos = (const float*)d_in[1];
    const int*   e_ind = (const int*)d_in[2];
    const int*   e_pos = (const int*)d_in[3];
    const float* w1i = (const float*)d_in[4];
    const float* as1i = (const float*)d_in[5];
    const float* ad1i = (const float*)d_in[6];
    const float* b1i = (const float*)d_in[7];
    const float* w2i = (const float*)d_in[8];
    const float* as2i = (const float*)d_in[9];
    const float* ad2i = (const float*)d_in[10];
    const float* b2i = (const float*)d_in[11];
    const float* w1p = (const float*)d_in[12];
    const float* as1p = (const float*)d_in[13];
    const float* ad1p = (const float*)d_in[14];
    const float* b1p = (const float*)d_in[15];
    const float* w2p = (const float*)d_in[16];
    const float* as2p = (const float*)d_in[17];
    const float* ad2p = (const float*)d_in[18];
    const float* b2p = (const float*)d_in[19];
    const float* fha = (const float*)d_in[20];
    const float* attw = (const float*)d_in[21];
    const float* mlpw = (const float*)d_in[22];
    const float* mlpb = (const float*)d_in[23];

    char* ws = (char*)d_ws;
    size_t off = 0;
    auto alloc = [&](size_t elems) { void* p = ws + off; off += elems * 4; return p; };

    const int n2 = 2 * N;
    const int nb = (n2 + BG - 1) / BG;             // 782

    __half* h16a = (__half*)alloc((size_t)n2 * ND / 2);  // layer-1 gemm fp16, 12.8 MB
    float* ssrc1 = (float*)alloc(n2);
    float* sdst1 = (float*)alloc(n2);
    float* sdst2 = (float*)alloc(n2);
    float* plog  = (float*)alloc(n2);
    float* satt  = (float*)alloc(n2);
    float* mmlp  = (float*)alloc(n2);
    float4* q2   = (float4*)alloc((size_t)4 * n2);      // packed (ssrc2, ta, tm), 1.6 MB
    int* deg    = (int*)alloc(n2);
    int* rowi   = (int*)alloc(n2);
    int* csr    = (int*)alloc((size_t)nb * CAP);        // 14.4 MB slabs
    int* bcursor= (int*)alloc(MAXB);
    int* part   = (int*)alloc((size_t)nb * CAP);        // 14.4 MB
    // h1 aliases part (12.8 <= 14.4 MB): part is dead after bucket_build,
    // before agg1_h writes h1.
    __half* h1 = (__half*)part;

    const int partBlocks  = (2 * E + PCH - 1) / PCH;        // 196
    const int gemm1Blocks = 2 * ((N + 63) / 64);            // 1564
    const int aggBlocks   = 2 * ((N + 15) / 16);            // 6250 (interleaved halves)
    const int gemm2Blocks = (N + 15) / 16;                  // 3125
    const int finBlocks   = (N + 255) / 256;                // 196

    // ---- CSR build overlapped with layer-1 gemm (independent work) ----
    hipMemsetAsync(bcursor, 0, MAXB * sizeof(int), stream);   // relative cursors
    part_gemm<<<partBlocks + gemm1Blocks, 1024, 0, stream>>>(
        e_ind, e_pos, bcursor, part,
        x_ind, x_pos, w1i, w1p, as1i, ad1i, as1p, ad1p,
        h16a, ssrc1, sdst1, N, E, nb, partBlocks);
    bucket_build<<<nb, 1024, 0, stream>>>(part, bcursor, rowi, deg, csr, n2, N);

    // ---- layer-1 aggregate (interleaved halves) -> fp16 halves + logits ----
    agg1_h<<<aggBlocks, 256, 0, stream>>>(
        csr, rowi, deg, ssrc1, sdst1, h16a, b1i, b1p, fha, h1, plog, N);

    // ---- layer-2 gemm with in-register first-hop combine -> packed q2 ----
    gemm2_combine<<<gemm2Blocks, 512, 0, stream>>>(
        h1, plog, w2i, w2p, as2i, ad2i, as2p, ad2p,
        attw, mlpw, q2, sdst2, N);

    // ---- layer-2 aggregate, packed-scalar (one 16 B load per edge) ----
    agg2_scal<<<aggBlocks, 256, 0, stream>>>(
        csr, rowi, deg, q2, sdst2, b2i, b2p, attw, mlpw, satt, mmlp, N);

    // ---- final branch softmax + bias ----
    final_combine<<<finBlocks, 256, 0, stream>>>(satt, mmlp, mlpb, (float*)d_out, N);
}